// Round 16
// baseline (35361.752 us; speedup 1.0000x reference)
//
#include <hip/hip_runtime.h>
#include <cstdint>
#include <cstddef>

#define BB 1024
#define SS 100
#define HH 256
#define CH 512          // rows per chunk (2 chunks) — fits ws ~270 MiB
#define NBLK 256        // persistent grid: 256 blocks x 512 threads = 1/CU
#define NGRP 32         // barrier tree: 32 groups x 8 blocks
#define BARSTRIDE 16    // u32 per 64B cacheline (padded counters)

// ---------------------------------------------------------------------------
// Bit-exact JAX threefry2x32 (partitionable mode — verified round 3)
// ---------------------------------------------------------------------------
__device__ __forceinline__ unsigned rotl32(unsigned v, int r) {
  return (v << r) | (v >> (32 - r));
}

__device__ __forceinline__ void threefry2x32(unsigned k0, unsigned k1,
                                             unsigned x0, unsigned x1,
                                             unsigned& o0, unsigned& o1) {
  unsigned k2 = k0 ^ k1 ^ 0x1BD11BDAu;
  x0 += k0; x1 += k1;
#define TF_R(r) { x0 += x1; x1 = rotl32(x1, (r)); x1 ^= x0; }
  TF_R(13) TF_R(15) TF_R(26) TF_R(6)
  x0 += k1; x1 += k2 + 1u;
  TF_R(17) TF_R(29) TF_R(16) TF_R(24)
  x0 += k2; x1 += k0 + 2u;
  TF_R(13) TF_R(15) TF_R(26) TF_R(6)
  x0 += k0; x1 += k1 + 3u;
  TF_R(17) TF_R(29) TF_R(16) TF_R(24)
  x0 += k1; x1 += k2 + 4u;
  TF_R(13) TF_R(15) TF_R(26) TF_R(6)
  x0 += k2; x1 += k0 + 5u;
#undef TF_R
  o0 = x0; o1 = x1;
}

__device__ __forceinline__ double sigd(double x) {
  return 1.0 / (1.0 + exp(-x));
}

// Fast fp32 tanh: 1 - 2/(e^{2x}+1).
__device__ __forceinline__ float tanh_fast(float x) {
  float e = __expf(2.0f * x);
  return 1.0f - 2.0f * __builtin_amdgcn_rcpf(e + 1.0f);
}

__device__ __forceinline__ double wave_max(double v) {
#pragma unroll
  for (int off = 32; off; off >>= 1) v = fmax(v, __shfl_xor(v, off));
  return v;
}
__device__ __forceinline__ double wave_sum(double v) {
#pragma unroll
  for (int off = 32; off; off >>= 1) v += __shfl_xor(v, off);
  return v;
}

// ---------------------------------------------------------------------------
// Tree grid barrier: NGRP group counters (8 blocks each) + root + generation,
// each on its own 64B line. Grid fully resident: 256 blocks x 512 thr =
// 1 block/CU on 256 CUs (launch_bounds(512,2) guarantees >=1 block/CU).
// bar layout (u32 idx): grp g at g*16 (g<32); root at 32*16; gen at 33*16.
// ---------------------------------------------------------------------------
__device__ __forceinline__ void grid_barrier(unsigned* bar) {
  __syncthreads();
  if (threadIdx.x == 0) {
    unsigned* gen = bar + 33 * BARSTRIDE;
    unsigned g = __hip_atomic_load(gen, __ATOMIC_RELAXED,
                                   __HIP_MEMORY_SCOPE_AGENT);
    __threadfence();
    unsigned* gc = bar + (blockIdx.x >> 3) * BARSTRIDE;
    unsigned a = __hip_atomic_fetch_add(gc, 1u, __ATOMIC_ACQ_REL,
                                        __HIP_MEMORY_SCOPE_AGENT);
    if (a + 1u == 8u) {
      __hip_atomic_store(gc, 0u, __ATOMIC_RELAXED,
                         __HIP_MEMORY_SCOPE_AGENT);
      unsigned* rc = bar + 32 * BARSTRIDE;
      unsigned r = __hip_atomic_fetch_add(rc, 1u, __ATOMIC_ACQ_REL,
                                          __HIP_MEMORY_SCOPE_AGENT);
      if (r + 1u == (unsigned)NGRP) {
        __hip_atomic_store(rc, 0u, __ATOMIC_RELAXED,
                           __HIP_MEMORY_SCOPE_AGENT);
        __hip_atomic_store(gen, g + 1u, __ATOMIC_RELEASE,
                           __HIP_MEMORY_SCOPE_AGENT);
      }
    }
    while (__hip_atomic_load(gen, __ATOMIC_RELAXED,
                             __HIP_MEMORY_SCOPE_AGENT) == g) {
      __builtin_amdgcn_s_sleep(8);
    }
    __threadfence();
  }
  __syncthreads();
}

// ---------------------------------------------------------------------------
__global__ __launch_bounds__(256) void init_chunk(
    double* __restrict__ h, double* __restrict__ c) {
  int i = blockIdx.x * 256 + threadIdx.x;
  h[i] = 0.0;
  c[i] = 0.0;
}

__global__ void zero_bar(unsigned* __restrict__ bar) {
  for (int i = threadIdx.x; i < 34 * BARSTRIDE; i += 256) bar[i] = 0u;
}

// ---------------------------------------------------------------------------
// Rank-2 embedding factorization precompute (fp64).
// P layout [7][1024]: 0..2 enc P0,P1,P2; 3..5 dec P0,P1,P2; 6 dec step-0 gates.
// ---------------------------------------------------------------------------
__global__ __launch_bounds__(256) void precompute_P(
    const float* __restrict__ emb_w, const float* __restrict__ emb_b,
    const float* __restrict__ start,
    const float* __restrict__ enc_wih, const float* __restrict__ dec_wih,
    double* __restrict__ P) {
  int idx = blockIdx.x * 256 + threadIdx.x;   // 0..7167
  int v = idx >> 10, n = idx & 1023;
  const float* W = (v < 3) ? enc_wih : dec_wih;
  int cm = (v < 6) ? (v % 3) : 3;
  const float* wr = W + (size_t)n * HH;
  double acc = 0.0;
  for (int k = 0; k < HH; ++k) {
    double cv;
    if (cm == 0)      cv = (double)emb_w[2 * k];
    else if (cm == 1) cv = (double)emb_w[2 * k + 1];
    else if (cm == 2) cv = (double)emb_b[k];
    else              cv = (double)start[k];
    acc = fma(cv, (double)wr[k], acc);
  }
  P[idx] = acc;
}

// Decoder init: zero mask + copy precomputed step-0 ih gates to every row.
__global__ __launch_bounds__(256) void init_dec(
    double* __restrict__ gih, int* __restrict__ mask,
    const double* __restrict__ gih0) {
  const int r = blockIdx.x, t = threadIdx.x;
  if (t < SS) mask[r * SS + t] = 0;
#pragma unroll
  for (int jj = 0; jj < 4; ++jj)
    gih[(size_t)r * 1024 + jj * 256 + t] = gih0[jj * 256 + t];
}

// WqT[k,t] = Wq[t,k]
__global__ __launch_bounds__(256) void transpose2(
    const float* __restrict__ a, const float* __restrict__ b,
    float* __restrict__ at, float* __restrict__ bt) {
  int k = blockIdx.x, t = threadIdx.x;
  at[k * HH + t] = a[t * HH + k];
  bt[k * HH + t] = b[t * HH + k];
}

// ---------------------------------------------------------------------------
// PERSISTENT ENCODER (chunk=512): 100 LSTM steps, 1 tree barrier per step.
// Block p: rows m0=(p&15)*32..+31, u-tile u0=(p>>4)*16. fp64, chains
// bit-identical to the verified per-step kernel.
// ---------------------------------------------------------------------------
__global__ __launch_bounds__(512, 2) void enc_persistent(
    const float* __restrict__ inputs, int cb,
    const double* __restrict__ Pe, const float* __restrict__ Whh,
    const float* __restrict__ bih, const float* __restrict__ bhh,
    double* __restrict__ hA, double* __restrict__ hB,
    double* __restrict__ c, float* __restrict__ enc_c,
    unsigned* __restrict__ bar) {
  __shared__ double As[16][34];
  __shared__ double Ws[16][66];
  const int tid = threadIdx.x;
  const int p = blockIdx.x;
  const int m0 = (p & 15) * 32;
  const int u0 = (p >> 4) * 16;
  const int r_loc = tid >> 4;
  const int tx = tid & 15;
  const int arow = tid >> 4, acol = tid & 15;
  const int wn = tid >> 3;
  const int wc2 = (tid & 7) * 2;
  const int wgate = wn >> 4, wu = wn & 15;
  const float* wrow = Whh + (size_t)(wgate * HH + u0 + wu) * HH;
  const int row = m0 + r_loc;
  const int u = u0 + tx;

  double* hin = hA;
  double* hout = hB;
#pragma unroll 1
  for (int t = 0; t < SS; ++t) {
    double i0 = (double)inputs[((cb + row) * SS + t) * 2];
    double i1 = (double)inputs[((cb + row) * SS + t) * 2 + 1];
    double acc[4];
#pragma unroll
    for (int j = 0; j < 4; ++j) {
      int n = j * 256 + u;
      acc[j] = fma(i0, Pe[n], fma(i1, Pe[1024 + n], Pe[2048 + n]));
    }
    double a_c; float2 w_c;
    a_c = hin[(size_t)(m0 + arow) * HH + acol];
    w_c = *(const float2*)(wrow + wc2);
#pragma unroll 1
    for (int s = 0; s < 16; ++s) {
      __syncthreads();
      As[acol][arow] = a_c;
      Ws[wc2][wn] = (double)w_c.x;
      Ws[wc2 + 1][wn] = (double)w_c.y;
      __syncthreads();
      if (s < 15) {
        int k0 = (s + 1) * 16;
        a_c = hin[(size_t)(m0 + arow) * HH + k0 + acol];
        w_c = *(const float2*)(wrow + k0 + wc2);
      }
#pragma unroll
      for (int kk = 0; kk < 16; ++kk) {
        double a = As[kk][r_loc];
#pragma unroll
        for (int j = 0; j < 4; ++j)
          acc[j] = fma(a, Ws[kk][j * 16 + tx], acc[j]);
      }
    }
    double gi = acc[0] + (double)bih[u] + (double)bhh[u];
    double gf = acc[1] + (double)bih[HH + u] + (double)bhh[HH + u];
    double gg = acc[2] + (double)bih[2 * HH + u] + (double)bhh[2 * HH + u];
    double go = acc[3] + (double)bih[3 * HH + u] + (double)bhh[3 * HH + u];
    size_t idx = (size_t)row * HH + u;
    double cp = c[idx];
    double cn = sigd(gf) * cp + sigd(gi) * tanh(gg);
    double hn = sigd(go) * tanh(cn);
    c[idx] = cn;
    hout[idx] = hn;
    enc_c[((size_t)row * SS + t) * HH + u] = (float)hn;

    if (t < SS - 1) grid_barrier(bar);
    double* tmp = hin; hin = hout; hout = tmp;
  }
  // SS even -> final h in hA
}

// ---------------------------------------------------------------------------
// PERSISTENT DECODER (chunk=512): 100 x {LSTM; barrier; attn+sample; barrier}.
// fp64 LSTM; attn 2 rows/block (half = tid>>8), mask block-local in LDS.
// ---------------------------------------------------------------------------
__global__ __launch_bounds__(512, 2) void dec_persistent(
    const float* __restrict__ inputs, int cb,
    double* __restrict__ gih, const double* __restrict__ Pd,
    const float* __restrict__ Whh,
    const float* __restrict__ bih, const float* __restrict__ bhh,
    double* __restrict__ hA, double* __restrict__ hB,
    double* __restrict__ c,
    const float* __restrict__ enc_c, const float* __restrict__ ref_g,
    const float* __restrict__ ref_p,
    const float* __restrict__ wqt_g, const float* __restrict__ bq_g,
    const float* __restrict__ vw_g, const float* __restrict__ vb_g,
    const float* __restrict__ wqt_p, const float* __restrict__ bq_p,
    const float* __restrict__ vw_p, const float* __restrict__ vb_p,
    float* __restrict__ out, unsigned* __restrict__ bar) {
  __shared__ double As[16][34];
  __shared__ double Ws[16][66];
  __shared__ __align__(16) float hqf[2][HH];
  __shared__ __align__(16) float qvf[2][HH];
  __shared__ double lg[2][SS];
  __shared__ float  lgw[2][SS];
  __shared__ int    smask[2][SS];
  __shared__ double redw[2][4];
  __shared__ int    ridxw[2][4];
  __shared__ int    sh_chosen[2];

  const int tid = threadIdx.x;
  const int p = blockIdx.x;
  // lstm roles
  const int m0 = (p & 15) * 32;
  const int u0 = (p >> 4) * 16;
  const int r_loc = tid >> 4;
  const int tx = tid & 15;
  const int arow = tid >> 4, acol = tid & 15;
  const int wn = tid >> 3;
  const int wc2 = (tid & 7) * 2;
  const int wgate = wn >> 4, wu = wn & 15;
  const float* wrow = Whh + (size_t)(wgate * HH + u0 + wu) * HH;
  const int lrow = m0 + r_loc;
  const int lu = u0 + tx;
  // attn roles
  const int half = tid >> 8;
  const int tl = tid & 255;
  const int wv4 = tl >> 6, l = tl & 63;
  const int ar = 2 * p + half;          // 0..511
  const int ab = cb + ar;               // global batch row

  if (tl < SS) smask[half][tl] = 0;

  double* hin = hA;
  double* hout = hB;

#pragma unroll 1
  for (int k = 0; k < SS; ++k) {
    // ================= LSTM phase (fp64) =================
    {
      double acc[4];
#pragma unroll
      for (int j = 0; j < 4; ++j)
        acc[j] = gih[(size_t)lrow * 1024 + j * 256 + lu];
      double a_c; float2 w_c;
      a_c = hin[(size_t)(m0 + arow) * HH + acol];
      w_c = *(const float2*)(wrow + wc2);
#pragma unroll 1
      for (int s = 0; s < 16; ++s) {
        __syncthreads();
        As[acol][arow] = a_c;
        Ws[wc2][wn] = (double)w_c.x;
        Ws[wc2 + 1][wn] = (double)w_c.y;
        __syncthreads();
        if (s < 15) {
          int k0 = (s + 1) * 16;
          a_c = hin[(size_t)(m0 + arow) * HH + k0 + acol];
          w_c = *(const float2*)(wrow + k0 + wc2);
        }
#pragma unroll
        for (int kk = 0; kk < 16; ++kk) {
          double a = As[kk][r_loc];
#pragma unroll
          for (int j = 0; j < 4; ++j)
            acc[j] = fma(a, Ws[kk][j * 16 + tx], acc[j]);
        }
      }
      double gi = acc[0] + (double)bih[lu] + (double)bhh[lu];
      double gf = acc[1] + (double)bih[HH + lu] + (double)bhh[HH + lu];
      double gg = acc[2] + (double)bih[2 * HH + lu] + (double)bhh[2 * HH + lu];
      double go = acc[3] + (double)bih[3 * HH + lu] + (double)bhh[3 * HH + lu];
      size_t idx = (size_t)lrow * HH + lu;
      double cp = c[idx];
      double cn = sigd(gf) * cp + sigd(gi) * tanh(gg);
      double hn = sigd(go) * tanh(cn);
      c[idx] = cn;
      hout[idx] = hn;
    }
    grid_barrier(bar);

    // ================= attn + sample phase =================
    hqf[half][tl] = (float)hout[(size_t)ar * HH + tl];
    __syncthreads();

    // glimpse query projection (fp32, 4-way ILP)
    {
      float a0 = 0.f, a1 = 0.f, a2 = 0.f, a3 = 0.f;
      for (int kk = 0; kk < HH; kk += 4) {
        a0 = fmaf(wqt_g[(kk + 0) * HH + tl], hqf[half][kk + 0], a0);
        a1 = fmaf(wqt_g[(kk + 1) * HH + tl], hqf[half][kk + 1], a1);
        a2 = fmaf(wqt_g[(kk + 2) * HH + tl], hqf[half][kk + 2], a2);
        a3 = fmaf(wqt_g[(kk + 3) * HH + tl], hqf[half][kk + 3], a3);
      }
      qvf[half][tl] = ((a0 + a1) + (a2 + a3)) + bq_g[tl];
    }
    __syncthreads();

    // glimpse logits
    {
      const float4 vg = *(const float4*)(vw_g + l * 4);
      const float4 qf = *(const float4*)(&qvf[half][l * 4]);
      const float vb = vb_g[0];
      for (int s = wv4; s < SS; s += 4) {
        if (smask[half][s]) {
          if (l == 0) lg[half][s] = -10.0;
          continue;
        }
        const float4 rp =
            *(const float4*)(ref_g + ((size_t)ar * SS + s) * HH + l * 4);
        float pp = tanh_fast(rp.x + qf.x) * vg.x;
        pp = fmaf(tanh_fast(rp.y + qf.y), vg.y, pp);
        pp = fmaf(tanh_fast(rp.z + qf.z), vg.z, pp);
        pp = fmaf(tanh_fast(rp.w + qf.w), vg.w, pp);
#pragma unroll
        for (int off = 32; off; off >>= 1) pp += __shfl_xor(pp, off);
        float z = 10.0f * tanh_fast(pp + vb);
        if (l == 0) lg[half][s] = (double)z;
      }
    }
    __syncthreads();

    // softmax -> fp32 weights (fp64 reduce)
    {
      double x = (tl < SS) ? lg[half][tl] : -1e300;
      double vm = wave_max(x);
      if (l == 0) redw[half][wv4] = vm;
      __syncthreads();
      double mx = fmax(fmax(redw[half][0], redw[half][1]),
                       fmax(redw[half][2], redw[half][3]));
      double e = (tl < SS) ? exp(x - mx) : 0.0;
      double vs = wave_sum(e);
      __syncthreads();
      if (l == 0) redw[half][wv4] = vs;
      __syncthreads();
      double sum = redw[half][0] + redw[half][1] + redw[half][2] +
                   redw[half][3];
      if (tl < SS) lgw[half][tl] = (float)(e / sum);
    }
    __syncthreads();

    // glimpse weighted sum of enc
    {
      const float* eb = enc_c + (size_t)ar * SS * HH + tl;
      float a0 = 0.f, a1 = 0.f, a2 = 0.f, a3 = 0.f;
      for (int s = 0; s < SS; s += 4) {
        a0 = fmaf(eb[(s + 0) * HH], lgw[half][s + 0], a0);
        a1 = fmaf(eb[(s + 1) * HH], lgw[half][s + 1], a1);
        a2 = fmaf(eb[(s + 2) * HH], lgw[half][s + 2], a2);
        a3 = fmaf(eb[(s + 3) * HH], lgw[half][s + 3], a3);
      }
      hqf[half][tl] = (a0 + a1) + (a2 + a3);
    }
    __syncthreads();

    // pointer query projection
    {
      float a0 = 0.f, a1 = 0.f, a2 = 0.f, a3 = 0.f;
      for (int kk = 0; kk < HH; kk += 4) {
        a0 = fmaf(wqt_p[(kk + 0) * HH + tl], hqf[half][kk + 0], a0);
        a1 = fmaf(wqt_p[(kk + 1) * HH + tl], hqf[half][kk + 1], a1);
        a2 = fmaf(wqt_p[(kk + 2) * HH + tl], hqf[half][kk + 2], a2);
        a3 = fmaf(wqt_p[(kk + 3) * HH + tl], hqf[half][kk + 3], a3);
      }
      qvf[half][tl] = ((a0 + a1) + (a2 + a3)) + bq_p[tl];
    }
    __syncthreads();

    // pointer logits
    {
      const float4 vg = *(const float4*)(vw_p + l * 4);
      const float4 qf = *(const float4*)(&qvf[half][l * 4]);
      const float vb = vb_p[0];
      for (int s = wv4; s < SS; s += 4) {
        if (smask[half][s]) {
          if (l == 0) lg[half][s] = -10.0;
          continue;
        }
        const float4 rp =
            *(const float4*)(ref_p + ((size_t)ar * SS + s) * HH + l * 4);
        float pp = tanh_fast(rp.x + qf.x) * vg.x;
        pp = fmaf(tanh_fast(rp.y + qf.y), vg.y, pp);
        pp = fmaf(tanh_fast(rp.z + qf.z), vg.z, pp);
        pp = fmaf(tanh_fast(rp.w + qf.w), vg.w, pp);
#pragma unroll
        for (int off = 32; off; off >>= 1) pp += __shfl_xor(pp, off);
        float z = 10.0f * tanh_fast(pp + vb);
        if (l == 0) lg[half][s] = (double)z;
      }
    }
    __syncthreads();

    // gumbel-argmax (exact threefry recipe, fp64)
    double x = (tl < SS) ? lg[half][tl] : -1e300;
    double val = -1e300;
    int idx = tl;
    if (tl < SS) {
      unsigned kk0, kk1;
      threefry2x32(0u, 42u, 0u, (unsigned)k, kk0, kk1);
      unsigned o0, o1;
      threefry2x32(kk0, kk1, 0u, (unsigned)(ab * SS + tl), o0, o1);
      unsigned bits = o0 ^ o1;
      double u = (double)(bits >> 9) * 0x1p-23;
      if (u == 0.0) u = 1.17549435e-38;
      val = x + (-log(-log(u)));
    }
#pragma unroll
    for (int off = 32; off; off >>= 1) {
      double v2 = __shfl_xor(val, off);
      int i2 = __shfl_xor(idx, off);
      if (v2 > val || (v2 == val && i2 < idx)) { val = v2; idx = i2; }
    }
    if (l == 0) { redw[half][wv4] = val; ridxw[half][wv4] = idx; }
    __syncthreads();
    if (tl == 0) {
      double bv = redw[half][0]; int bi = ridxw[half][0];
#pragma unroll
      for (int i = 1; i < 4; ++i) {
        if (redw[half][i] > bv ||
            (redw[half][i] == bv && ridxw[half][i] < bi)) {
          bv = redw[half][i]; bi = ridxw[half][i];
        }
      }
      sh_chosen[half] = bi;
    }
    __syncthreads();
    int chosen = sh_chosen[half];

    // log-softmax + outputs + mask update
    {
      double vm = wave_max(x);
      if (l == 0) redw[half][wv4] = vm;
      __syncthreads();
      double mx = fmax(fmax(redw[half][0], redw[half][1]),
                       fmax(redw[half][2], redw[half][3]));
      double e = (tl < SS) ? exp(x - mx) : 0.0;
      double vs = wave_sum(e);
      __syncthreads();
      if (l == 0) redw[half][wv4] = vs;
      __syncthreads();
      if (tl == 0) {
        double sum = redw[half][0] + redw[half][1] + redw[half][2] +
                     redw[half][3];
        double lse = log(sum);
        double xc = lg[half][chosen];
        out[(size_t)ab * SS + k] = (float)(xc - mx - lse);
        out[(size_t)BB * SS + (size_t)ab * SS + k] = (float)chosen;
        smask[half][chosen] = 1;
      }
    }

    // next-step ih gates via rank-2 embedding (fp64)
    {
      int ib = (ab * SS + chosen) * 2;
      double i0 = (double)inputs[ib], i1 = (double)inputs[ib + 1];
#pragma unroll
      for (int jj = 0; jj < 4; ++jj) {
        int n = jj * 256 + tl;
        gih[(size_t)ar * 1024 + n] =
            fma(i0, Pd[n], fma(i1, Pd[1024 + n], Pd[2048 + n]));
      }
    }

    if (k < SS - 1) grid_barrier(bar);
    double* tmp = hin; hin = hout; hout = tmp;
  }
}

// ---------------------------------------------------------------------------
// Ref projection (fp32 math): C[m,n] = sum_k A[m,k]*W[n,k] + b[n].
// Output stored fp32 regardless; fp32 compute perturbs pre-quantization
// values ~1e-6 rel, once (no recurrence) — smaller than the verified-safe
// R4->R5 fp32 attn class (absmax pinned 0.03125 across 7 passing rounds).
// ---------------------------------------------------------------------------
__global__ __launch_bounds__(256) void proj_gemm(
    const float* __restrict__ A, const float* __restrict__ W,
    const float* __restrict__ bias, float* __restrict__ C) {
  __shared__ float As[16][68];
  __shared__ float Ws[16][68];
  const int tid = threadIdx.x;
  const int tx = tid & 15, ty = tid >> 4;
  const int m0 = blockIdx.x * 64;
  const int n0 = blockIdx.y * 64;
  const int lrow = tid >> 2;
  const int lcol = (tid & 3) << 2;
  float acc[4][4] = {};

  const float* ar = A + (size_t)(m0 + lrow) * HH;
  const float* wr = W + (size_t)(n0 + lrow) * HH;
  for (int k0 = 0; k0 < HH; k0 += 16) {
    float4 av = *(const float4*)(ar + k0 + lcol);
    float4 wv = *(const float4*)(wr + k0 + lcol);
    __syncthreads();
    As[lcol + 0][lrow] = av.x; As[lcol + 1][lrow] = av.y;
    As[lcol + 2][lrow] = av.z; As[lcol + 3][lrow] = av.w;
    Ws[lcol + 0][lrow] = wv.x; Ws[lcol + 1][lrow] = wv.y;
    Ws[lcol + 2][lrow] = wv.z; Ws[lcol + 3][lrow] = wv.w;
    __syncthreads();
#pragma unroll
    for (int kk = 0; kk < 16; ++kk) {
      float a[4], w[4];
#pragma unroll
      for (int i = 0; i < 4; ++i) a[i] = As[kk][ty * 4 + i];
#pragma unroll
      for (int j = 0; j < 4; ++j) w[j] = Ws[kk][tx * 4 + j];
#pragma unroll
      for (int i = 0; i < 4; ++i)
#pragma unroll
        for (int j = 0; j < 4; ++j) acc[i][j] = fmaf(a[i], w[j], acc[i][j]);
    }
  }
#pragma unroll
  for (int i = 0; i < 4; ++i) {
    float* crow = C + (size_t)(m0 + ty * 4 + i) * HH + n0 + tx * 4;
#pragma unroll
    for (int j = 0; j < 4; ++j)
      crow[j] = acc[i][j] + bias[n0 + tx * 4 + j];
  }
}

// Diagnostic: encode ws_size (MB) into output so absmax reveals it.
__global__ __launch_bounds__(256) void diag_kernel(float* __restrict__ out, float v) {
  int i = blockIdx.x * 256 + threadIdx.x;
  if (i < 2 * BB * SS) out[i] = v;
}

// ---------------------------------------------------------------------------
extern "C" void kernel_launch(void* const* d_in, const int* in_sizes, int n_in,
                              void* d_out, int out_size, void* d_ws, size_t ws_size,
                              hipStream_t stream) {
  (void)in_sizes; (void)n_in; (void)out_size;
  const float* inputs    = (const float*)d_in[0];
  const float* emb_w     = (const float*)d_in[1];
  const float* emb_b     = (const float*)d_in[2];
  const float* enc_wih   = (const float*)d_in[3];
  const float* enc_whh   = (const float*)d_in[4];
  const float* enc_bih   = (const float*)d_in[5];
  const float* enc_bhh   = (const float*)d_in[6];
  const float* dec_wih   = (const float*)d_in[7];
  const float* dec_whh   = (const float*)d_in[8];
  const float* dec_bih   = (const float*)d_in[9];
  const float* dec_bhh   = (const float*)d_in[10];
  const float* ptr_wq_w  = (const float*)d_in[11];
  const float* ptr_wq_b  = (const float*)d_in[12];
  const float* ptr_wref_w= (const float*)d_in[13];
  const float* ptr_wref_b= (const float*)d_in[14];
  const float* ptr_v_w   = (const float*)d_in[15];
  const float* ptr_v_b   = (const float*)d_in[16];
  const float* glm_wq_w  = (const float*)d_in[17];
  const float* glm_wq_b  = (const float*)d_in[18];
  const float* glm_wref_w= (const float*)d_in[19];
  const float* glm_wref_b= (const float*)d_in[20];
  const float* glm_v_w   = (const float*)d_in[21];
  const float* glm_v_b   = (const float*)d_in[22];
  const float* start     = (const float*)d_in[23];
  float* out = (float*)d_out;

  // Workspace (chunk=512 persistent): ~158 MiB — fits the 270 MiB pods.
  auto al = [](size_t n) { return (n + 255) & ~(size_t)255; };
  const size_t need =
      3 * al((size_t)CH * SS * HH * 4) +       // enc_c, ref_g, ref_p
      3 * al((size_t)CH * HH * 8) +            // hA, hB, cbuf
      al((size_t)CH * 1024 * 8) +              // gih
      al((size_t)CH * SS * 4) +                // mask
      2 * al((size_t)HH * HH * 4) +            // wqt_g, wqt_p
      al((size_t)7 * 1024 * 8) +               // P
      al(34 * BARSTRIDE * 4);                  // barrier
  if (ws_size < need) {
    diag_kernel<<<(2 * BB * SS + 255) / 256, 256, 0, stream>>>(
        out, (float)(ws_size >> 20));
    return;
  }

  char* base_p = (char*)d_ws;
  size_t off = 0;
  auto take = [&](size_t nbytes) {
    void* p = base_p + off;
    off = (off + nbytes + 255) & ~(size_t)255;
    return p;
  };
  float*  enc_c  = (float*)take((size_t)CH * SS * HH * 4);
  float*  ref_g  = (float*)take((size_t)CH * SS * HH * 4);
  float*  ref_p  = (float*)take((size_t)CH * SS * HH * 4);
  double* hA     = (double*)take((size_t)CH * HH * 8);
  double* hB     = (double*)take((size_t)CH * HH * 8);
  double* cbuf   = (double*)take((size_t)CH * HH * 8);
  double* gih    = (double*)take((size_t)CH * 1024 * 8);
  int*    mask   = (int*)take((size_t)CH * SS * 4);
  float*  wqt_g  = (float*)take((size_t)HH * HH * 4);
  float*  wqt_p  = (float*)take((size_t)HH * HH * 4);
  double* P      = (double*)take((size_t)7 * 1024 * 8);
  unsigned* bar  = (unsigned*)take(34 * BARSTRIDE * 4);

  transpose2<<<HH, HH, 0, stream>>>(glm_wq_w, ptr_wq_w, wqt_g, wqt_p);
  precompute_P<<<28, 256, 0, stream>>>(emb_w, emb_b, start, enc_wih, dec_wih, P);
  zero_bar<<<1, 256, 0, stream>>>(bar);

  const double* Pe   = P;
  const double* Pd   = P + 3 * 1024;
  const double* gih0 = P + 6 * 1024;

  for (int cb = 0; cb < BB; cb += CH) {
    // ---- encoder: persistent, 99 grid barriers ----
    init_chunk<<<CH, 256, 0, stream>>>(hA, cbuf);
    enc_persistent<<<NBLK, 512, 0, stream>>>(
        inputs, cb, Pe, enc_whh, enc_bih, enc_bhh, hA, hB, cbuf, enc_c, bar);

    // ---- ref projections (fp32) ----
    proj_gemm<<<dim3(CH * SS / 64, 4), 256, 0, stream>>>(
        enc_c, glm_wref_w, glm_wref_b, ref_g);
    proj_gemm<<<dim3(CH * SS / 64, 4), 256, 0, stream>>>(
        enc_c, ptr_wref_w, ptr_wref_b, ref_p);

    // ---- decoder: persistent, 199 grid barriers ----
    init_dec<<<CH, 256, 0, stream>>>(gih, mask, gih0);
    // SS even -> encoder final h in hA
    dec_persistent<<<NBLK, 512, 0, stream>>>(
        inputs, cb, gih, Pd, dec_whh, dec_bih, dec_bhh, hA, hB, cbuf,
        enc_c, ref_g, ref_p,
        wqt_g, glm_wq_b, glm_v_w, glm_v_b,
        wqt_p, ptr_wq_b, ptr_v_w, ptr_v_b, out, bar);
  }
}

// Round 17
// 17282.845 us; speedup vs baseline: 2.0461x; 2.0461x over previous
//
#include <hip/hip_runtime.h>
#include <cstdint>
#include <cstddef>

#define BB 1024
#define SS 100
#define HH 256

// ---------------------------------------------------------------------------
// Bit-exact JAX threefry2x32 (partitionable mode — verified round 3)
// ---------------------------------------------------------------------------
__device__ __forceinline__ unsigned rotl32(unsigned v, int r) {
  return (v << r) | (v >> (32 - r));
}

__device__ __forceinline__ void threefry2x32(unsigned k0, unsigned k1,
                                             unsigned x0, unsigned x1,
                                             unsigned& o0, unsigned& o1) {
  unsigned k2 = k0 ^ k1 ^ 0x1BD11BDAu;
  x0 += k0; x1 += k1;
#define TF_R(r) { x0 += x1; x1 = rotl32(x1, (r)); x1 ^= x0; }
  TF_R(13) TF_R(15) TF_R(26) TF_R(6)
  x0 += k1; x1 += k2 + 1u;
  TF_R(17) TF_R(29) TF_R(16) TF_R(24)
  x0 += k2; x1 += k0 + 2u;
  TF_R(13) TF_R(15) TF_R(26) TF_R(6)
  x0 += k0; x1 += k1 + 3u;
  TF_R(17) TF_R(29) TF_R(16) TF_R(24)
  x0 += k1; x1 += k2 + 4u;
  TF_R(13) TF_R(15) TF_R(26) TF_R(6)
  x0 += k2; x1 += k0 + 5u;
#undef TF_R
  o0 = x0; o1 = x1;
}

__device__ __forceinline__ double sigd(double x) {
  return 1.0 / (1.0 + exp(-x));
}

// Fast fp32 tanh: 1 - 2/(e^{2x}+1).
__device__ __forceinline__ float tanh_fast(float x) {
  float e = __expf(2.0f * x);
  return 1.0f - 2.0f * __builtin_amdgcn_rcpf(e + 1.0f);
}

__device__ __forceinline__ double wave_max(double v) {
#pragma unroll
  for (int off = 32; off; off >>= 1) v = fmax(v, __shfl_xor(v, off));
  return v;
}
__device__ __forceinline__ double wave_sum(double v) {
#pragma unroll
  for (int off = 32; off; off >>= 1) v += __shfl_xor(v, off);
  return v;
}

// ---------------------------------------------------------------------------
__global__ __launch_bounds__(256) void init_chunk(
    double* __restrict__ h, double* __restrict__ c) {
  int i = blockIdx.x * 256 + threadIdx.x;
  h[i] = 0.0;
  c[i] = 0.0;
}

// ---------------------------------------------------------------------------
// Rank-2 embedding factorization precompute (fp64).
// P layout [7][1024]: 0..2 enc P0,P1,P2; 3..5 dec P0,P1,P2; 6 dec step-0 gates.
// ---------------------------------------------------------------------------
__global__ __launch_bounds__(256) void precompute_P(
    const float* __restrict__ emb_w, const float* __restrict__ emb_b,
    const float* __restrict__ start,
    const float* __restrict__ enc_wih, const float* __restrict__ dec_wih,
    double* __restrict__ P) {
  int idx = blockIdx.x * 256 + threadIdx.x;   // 0..7167
  int v = idx >> 10, n = idx & 1023;
  const float* W = (v < 3) ? enc_wih : dec_wih;
  int cm = (v < 6) ? (v % 3) : 3;
  const float* wr = W + (size_t)n * HH;
  double acc = 0.0;
  for (int k = 0; k < HH; ++k) {
    double cv;
    if (cm == 0)      cv = (double)emb_w[2 * k];
    else if (cm == 1) cv = (double)emb_w[2 * k + 1];
    else if (cm == 2) cv = (double)emb_b[k];
    else              cv = (double)start[k];
    acc = fma(cv, (double)wr[k], acc);
  }
  P[idx] = acc;
}

// Decoder init: zero mask + copy precomputed step-0 ih gates to every row.
__global__ __launch_bounds__(256) void init_dec(
    double* __restrict__ gih, int* __restrict__ mask,
    const double* __restrict__ gih0) {
  const int r = blockIdx.x, t = threadIdx.x;
  if (t < SS) mask[r * SS + t] = 0;
#pragma unroll
  for (int jj = 0; jj < 4; ++jj)
    gih[(size_t)r * 1024 + jj * 256 + t] = gih0[jj * 256 + t];
}

// WqT[k,t] = Wq[t,k]
__global__ __launch_bounds__(256) void transpose2(
    const float* __restrict__ a, const float* __restrict__ b,
    float* __restrict__ at, float* __restrict__ bt) {
  int k = blockIdx.x, t = threadIdx.x;
  at[k * HH + t] = a[t * HH + k];
  bt[k * HH + t] = b[t * HH + k];
}

// ---------------------------------------------------------------------------
// Fused LSTM step — hh phase only (16 slabs); input-gate contribution via acc
// init (encoder: rank-2 embed from Pe; decoder: gih from attn epilogue).
// Tile: 32 rows x 16 u-cols x 4 gates. Thread: 2 rows x 4 gates of one u.
// Grid: (chunk/32, 16). Math fp64; slab s+1 prefetched into registers.
// (Verified R7/R9/R11/R15 form — bit-identical chains.)
// ---------------------------------------------------------------------------
template <bool EMBED>
__global__ __launch_bounds__(256) void lstm_gates(
    const float* __restrict__ inputs, int t, int cb,
    const double* __restrict__ gih, const double* __restrict__ Pe,
    const float* __restrict__ Whh,
    const float* __restrict__ bih, const float* __restrict__ bhh,
    const double* __restrict__ hprev, double* __restrict__ hnew,
    double* __restrict__ c, float* __restrict__ enc_c) {
  __shared__ double As[16][34];
  __shared__ double Ws[16][66];
  const int tid = threadIdx.x;
  const int tx = tid & 15;
  const int ty = tid >> 4;
  const int m0 = blockIdx.x * 32;
  const int u0 = blockIdx.y * 16;
  const int arow = tid >> 3;
  const int acol = (tid & 7) * 2;
  const int wn   = tid >> 2;
  const int wcol = (tid & 3) * 4;
  const int wgate = wn >> 4, wu = wn & 15;
  double acc[2][4];

  if (EMBED) {
#pragma unroll
    for (int i = 0; i < 2; ++i) {
      int bb = cb + m0 + ty * 2 + i;
      double i0 = (double)inputs[(bb * SS + t) * 2];
      double i1 = (double)inputs[(bb * SS + t) * 2 + 1];
#pragma unroll
      for (int j = 0; j < 4; ++j) {
        int n = j * 256 + u0 + tx;
        acc[i][j] = fma(i0, Pe[n], fma(i1, Pe[1024 + n], Pe[2048 + n]));
      }
    }
  } else {
#pragma unroll
    for (int i = 0; i < 2; ++i) {
      const double* gr = gih + (size_t)(m0 + ty * 2 + i) * 1024 + u0 + tx;
#pragma unroll
      for (int j = 0; j < 4; ++j) acc[i][j] = gr[j * 256];
    }
  }

  const float* wrow_hh = Whh + (size_t)(wgate * HH + u0 + wu) * HH;
  auto load_slab = [&](int s, double& a0, double& a1, float4& wv) {
    const int k0 = s * 16;
    const double* ar = hprev + (size_t)(m0 + arow) * HH + k0 + acol;
    a0 = ar[0]; a1 = ar[1];
    wv = *(const float4*)(wrow_hh + k0 + wcol);
  };

  double a0c, a1c; float4 wvc;
  load_slab(0, a0c, a1c, wvc);
  for (int s = 0; s < 16; ++s) {
    __syncthreads();
    As[acol][arow] = a0c;
    As[acol + 1][arow] = a1c;
    Ws[wcol + 0][wn] = (double)wvc.x;
    Ws[wcol + 1][wn] = (double)wvc.y;
    Ws[wcol + 2][wn] = (double)wvc.z;
    Ws[wcol + 3][wn] = (double)wvc.w;
    __syncthreads();
    if (s < 15) load_slab(s + 1, a0c, a1c, wvc);
#pragma unroll
    for (int kk = 0; kk < 16; ++kk) {
      double a0k = As[kk][ty * 2];
      double a1k = As[kk][ty * 2 + 1];
#pragma unroll
      for (int j = 0; j < 4; ++j) {
        double w = Ws[kk][j * 16 + tx];
        acc[0][j] = fma(a0k, w, acc[0][j]);
        acc[1][j] = fma(a1k, w, acc[1][j]);
      }
    }
  }

  const int u = u0 + tx;
#pragma unroll
  for (int i = 0; i < 2; ++i) {
    int r = m0 + ty * 2 + i;
    double gi = acc[i][0] + (double)bih[u] + (double)bhh[u];
    double gf = acc[i][1] + (double)bih[HH + u] + (double)bhh[HH + u];
    double gg = acc[i][2] + (double)bih[2 * HH + u] + (double)bhh[2 * HH + u];
    double go = acc[i][3] + (double)bih[3 * HH + u] + (double)bhh[3 * HH + u];
    size_t idx = (size_t)r * HH + u;
    double cp = c[idx];
    double cn = sigd(gf) * cp + sigd(gi) * tanh(gg);
    double hn = sigd(go) * tanh(cn);
    c[idx] = cn;
    hnew[idx] = hn;
    if (enc_c) enc_c[((size_t)r * SS + t) * HH + u] = (float)hn;
  }
}

// ---------------------------------------------------------------------------
// Fused decoder attention + sampling (verified R7/R15 form: 1 row/block,
// 4 waves split the s-loop; rank-2 ih-gate epilogue).
// ---------------------------------------------------------------------------
__global__ __launch_bounds__(256) void dec_attn_sample(
    const double* __restrict__ h,
    const float* __restrict__ enc_c, const float* __restrict__ ref_g,
    const float* __restrict__ ref_p,
    const float* __restrict__ wqt_g, const float* __restrict__ bq_g,
    const float* __restrict__ vw_g, const float* __restrict__ vb_g,
    const float* __restrict__ wqt_p, const float* __restrict__ bq_p,
    const float* __restrict__ vw_p, const float* __restrict__ vb_p,
    int* __restrict__ mask, double* __restrict__ gih,
    const double* __restrict__ Pd,
    const float* __restrict__ inputs,
    float* __restrict__ out, int step, int cb) {
  __shared__ float  hqf[HH];
  __shared__ __align__(16) float qvf[HH];
  __shared__ double lg[SS];
  __shared__ float  lgw[SS];
  __shared__ int    smask[SS];
  __shared__ double redw[4];
  __shared__ int    ridxw[4];
  __shared__ int    sh_chosen;

  const int r = blockIdx.x, t = threadIdx.x;
  const int w = t >> 6, l = t & 63;
  const int b = cb + r;

  hqf[t] = (float)h[(size_t)r * HH + t];
  if (t < SS) smask[t] = mask[r * SS + t];
  __syncthreads();

  // ---- glimpse query projection (fp32, 4-way ILP) ----
  {
    float a0 = 0.f, a1 = 0.f, a2 = 0.f, a3 = 0.f;
    for (int k = 0; k < HH; k += 4) {
      a0 = fmaf(wqt_g[(k + 0) * HH + t], hqf[k + 0], a0);
      a1 = fmaf(wqt_g[(k + 1) * HH + t], hqf[k + 1], a1);
      a2 = fmaf(wqt_g[(k + 2) * HH + t], hqf[k + 2], a2);
      a3 = fmaf(wqt_g[(k + 3) * HH + t], hqf[k + 3], a3);
    }
    qvf[t] = ((a0 + a1) + (a2 + a3)) + bq_g[t];
  }
  __syncthreads();

  // ---- glimpse logits ----
  {
    const float4 vg = *(const float4*)(vw_g + l * 4);
    const float4 qf = *(const float4*)(qvf + l * 4);
    const float vb = vb_g[0];
    for (int s = w; s < SS; s += 4) {
      if (smask[s]) {
        if (l == 0) lg[s] = -10.0;
        continue;
      }
      const float4 rp = *(const float4*)(ref_g + ((size_t)r * SS + s) * HH + l * 4);
      float p = tanh_fast(rp.x + qf.x) * vg.x;
      p = fmaf(tanh_fast(rp.y + qf.y), vg.y, p);
      p = fmaf(tanh_fast(rp.z + qf.z), vg.z, p);
      p = fmaf(tanh_fast(rp.w + qf.w), vg.w, p);
#pragma unroll
      for (int off = 32; off; off >>= 1) p += __shfl_xor(p, off);
      float z = 10.0f * tanh_fast(p + vb);
      if (l == 0) lg[s] = (double)z;
    }
  }
  __syncthreads();

  // ---- softmax -> fp32 weights (fp64 reduce) ----
  {
    double x = (t < SS) ? lg[t] : -1e300;
    double vm = wave_max(x);
    if (l == 0) redw[w] = vm;
    __syncthreads();
    double mx = fmax(fmax(redw[0], redw[1]), fmax(redw[2], redw[3]));
    double e = (t < SS) ? exp(x - mx) : 0.0;
    double vs = wave_sum(e);
    __syncthreads();
    if (l == 0) redw[w] = vs;
    __syncthreads();
    double sum = redw[0] + redw[1] + redw[2] + redw[3];
    if (t < SS) lgw[t] = (float)(e / sum);
  }
  __syncthreads();

  // ---- glimpse weighted sum of enc (fp32) ----
  {
    const float* eb = enc_c + (size_t)r * SS * HH + t;
    float acc0 = 0.f, acc1 = 0.f, acc2 = 0.f, acc3 = 0.f;
    for (int s = 0; s < SS; s += 4) {
      acc0 = fmaf(eb[(s + 0) * HH], lgw[s + 0], acc0);
      acc1 = fmaf(eb[(s + 1) * HH], lgw[s + 1], acc1);
      acc2 = fmaf(eb[(s + 2) * HH], lgw[s + 2], acc2);
      acc3 = fmaf(eb[(s + 3) * HH], lgw[s + 3], acc3);
    }
    hqf[t] = (acc0 + acc1) + (acc2 + acc3);
  }
  __syncthreads();

  // ---- pointer query projection (fp32) ----
  {
    float a0 = 0.f, a1 = 0.f, a2 = 0.f, a3 = 0.f;
    for (int k = 0; k < HH; k += 4) {
      a0 = fmaf(wqt_p[(k + 0) * HH + t], hqf[k + 0], a0);
      a1 = fmaf(wqt_p[(k + 1) * HH + t], hqf[k + 1], a1);
      a2 = fmaf(wqt_p[(k + 2) * HH + t], hqf[k + 2], a2);
      a3 = fmaf(wqt_p[(k + 3) * HH + t], hqf[k + 3], a3);
    }
    qvf[t] = ((a0 + a1) + (a2 + a3)) + bq_p[t];
  }
  __syncthreads();

  // ---- pointer logits ----
  {
    const float4 vg = *(const float4*)(vw_p + l * 4);
    const float4 qf = *(const float4*)(qvf + l * 4);
    const float vb = vb_p[0];
    for (int s = w; s < SS; s += 4) {
      if (smask[s]) {
        if (l == 0) lg[s] = -10.0;
        continue;
      }
      const float4 rp = *(const float4*)(ref_p + ((size_t)r * SS + s) * HH + l * 4);
      float p = tanh_fast(rp.x + qf.x) * vg.x;
      p = fmaf(tanh_fast(rp.y + qf.y), vg.y, p);
      p = fmaf(tanh_fast(rp.z + qf.z), vg.z, p);
      p = fmaf(tanh_fast(rp.w + qf.w), vg.w, p);
#pragma unroll
      for (int off = 32; off; off >>= 1) p += __shfl_xor(p, off);
      float z = 10.0f * tanh_fast(p + vb);
      if (l == 0) lg[s] = (double)z;
    }
  }
  __syncthreads();

  // ---- gumbel-argmax (exact threefry recipe, fp64) ----
  double x = (t < SS) ? lg[t] : -1e300;
  double val = -1e300;
  int idx = t;
  if (t < SS) {
    unsigned kk0, kk1;
    threefry2x32(0u, 42u, 0u, (unsigned)step, kk0, kk1);
    unsigned j = (unsigned)(b * SS + t);
    unsigned o0, o1;
    threefry2x32(kk0, kk1, 0u, j, o0, o1);
    unsigned bits = o0 ^ o1;
    double u = (double)(bits >> 9) * 0x1p-23;
    if (u == 0.0) u = 1.17549435e-38;
    val = x + (-log(-log(u)));
  }
#pragma unroll
  for (int off = 32; off; off >>= 1) {
    double v2 = __shfl_xor(val, off);
    int i2 = __shfl_xor(idx, off);
    if (v2 > val || (v2 == val && i2 < idx)) { val = v2; idx = i2; }
  }
  if (l == 0) { redw[w] = val; ridxw[w] = idx; }
  __syncthreads();
  if (t == 0) {
    double bv = redw[0]; int bi = ridxw[0];
#pragma unroll
    for (int i = 1; i < 4; ++i) {
      if (redw[i] > bv || (redw[i] == bv && ridxw[i] < bi)) {
        bv = redw[i]; bi = ridxw[i];
      }
    }
    sh_chosen = bi;
  }
  __syncthreads();
  int chosen = sh_chosen;

  // ---- log-softmax pieces (fp64, wave reduce) ----
  {
    double vm = wave_max(x);
    if (l == 0) redw[w] = vm;
    __syncthreads();
    double mx = fmax(fmax(redw[0], redw[1]), fmax(redw[2], redw[3]));
    double e = (t < SS) ? exp(x - mx) : 0.0;
    double vs = wave_sum(e);
    __syncthreads();
    if (l == 0) redw[w] = vs;
    __syncthreads();
    if (t == 0) {
      double sum = redw[0] + redw[1] + redw[2] + redw[3];
      double lse = log(sum);
      double xc = lg[chosen];
      out[(size_t)b * SS + step] = (float)(xc - mx - lse);
      out[(size_t)BB * SS + (size_t)b * SS + step] = (float)chosen;
      mask[r * SS + chosen] = 1;
    }
  }

  // ---- next-step ih gates via rank-2 embedding (fp64) ----
  int ib = (b * SS + chosen) * 2;
  double i0 = (double)inputs[ib], i1 = (double)inputs[ib + 1];
#pragma unroll
  for (int jj = 0; jj < 4; ++jj) {
    int n = jj * 256 + t;
    gih[(size_t)r * 1024 + n] =
        fma(i0, Pd[n], fma(i1, Pd[1024 + n], Pd[2048 + n]));
  }
}

// ---------------------------------------------------------------------------
// Ref projection (fp32 math — HW-verified safe in R16: ran with absmax
// pinned at 0.03125): C[m,n] = sum_k A[m,k]*W[n,k] + b[n].
// ---------------------------------------------------------------------------
__global__ __launch_bounds__(256) void proj_gemm(
    const float* __restrict__ A, const float* __restrict__ W,
    const float* __restrict__ bias, float* __restrict__ C) {
  __shared__ float As[16][68];
  __shared__ float Ws[16][68];
  const int tid = threadIdx.x;
  const int tx = tid & 15, ty = tid >> 4;
  const int m0 = blockIdx.x * 64;
  const int n0 = blockIdx.y * 64;
  const int lrow = tid >> 2;
  const int lcol = (tid & 3) << 2;
  float acc[4][4] = {};

  const float* ar = A + (size_t)(m0 + lrow) * HH;
  const float* wr = W + (size_t)(n0 + lrow) * HH;
  for (int k0 = 0; k0 < HH; k0 += 16) {
    float4 av = *(const float4*)(ar + k0 + lcol);
    float4 wv = *(const float4*)(wr + k0 + lcol);
    __syncthreads();
    As[lcol + 0][lrow] = av.x; As[lcol + 1][lrow] = av.y;
    As[lcol + 2][lrow] = av.z; As[lcol + 3][lrow] = av.w;
    Ws[lcol + 0][lrow] = wv.x; Ws[lcol + 1][lrow] = wv.y;
    Ws[lcol + 2][lrow] = wv.z; Ws[lcol + 3][lrow] = wv.w;
    __syncthreads();
#pragma unroll
    for (int kk = 0; kk < 16; ++kk) {
      float a[4], w[4];
#pragma unroll
      for (int i = 0; i < 4; ++i) a[i] = As[kk][ty * 4 + i];
#pragma unroll
      for (int j = 0; j < 4; ++j) w[j] = Ws[kk][tx * 4 + j];
#pragma unroll
      for (int i = 0; i < 4; ++i)
#pragma unroll
        for (int j = 0; j < 4; ++j) acc[i][j] = fmaf(a[i], w[j], acc[i][j]);
    }
  }
#pragma unroll
  for (int i = 0; i < 4; ++i) {
    float* crow = C + (size_t)(m0 + ty * 4 + i) * HH + n0 + tx * 4;
#pragma unroll
    for (int j = 0; j < 4; ++j)
      crow[j] = acc[i][j] + bias[n0 + tx * 4 + j];
  }
}

// Diagnostic: encode ws_size (MB) into output so absmax reveals it.
__global__ __launch_bounds__(256) void diag_kernel(float* __restrict__ out, float v) {
  int i = blockIdx.x * 256 + threadIdx.x;
  if (i < 2 * BB * SS) out[i] = v;
}

// ---------------------------------------------------------------------------
extern "C" void kernel_launch(void* const* d_in, const int* in_sizes, int n_in,
                              void* d_out, int out_size, void* d_ws, size_t ws_size,
                              hipStream_t stream) {
  (void)in_sizes; (void)n_in; (void)out_size;
  const float* inputs    = (const float*)d_in[0];
  const float* emb_w     = (const float*)d_in[1];
  const float* emb_b     = (const float*)d_in[2];
  const float* enc_wih   = (const float*)d_in[3];
  const float* enc_whh   = (const float*)d_in[4];
  const float* enc_bih   = (const float*)d_in[5];
  const float* enc_bhh   = (const float*)d_in[6];
  const float* dec_wih   = (const float*)d_in[7];
  const float* dec_whh   = (const float*)d_in[8];
  const float* dec_bih   = (const float*)d_in[9];
  const float* dec_bhh   = (const float*)d_in[10];
  const float* ptr_wq_w  = (const float*)d_in[11];
  const float* ptr_wq_b  = (const float*)d_in[12];
  const float* ptr_wref_w= (const float*)d_in[13];
  const float* ptr_wref_b= (const float*)d_in[14];
  const float* ptr_v_w   = (const float*)d_in[15];
  const float* ptr_v_b   = (const float*)d_in[16];
  const float* glm_wq_w  = (const float*)d_in[17];
  const float* glm_wq_b  = (const float*)d_in[18];
  const float* glm_wref_w= (const float*)d_in[19];
  const float* glm_wref_b= (const float*)d_in[20];
  const float* glm_v_w   = (const float*)d_in[21];
  const float* glm_v_b   = (const float*)d_in[22];
  const float* start     = (const float*)d_in[23];
  float* out = (float*)d_out;

  // Workspace: chunk=512 (~158 MiB, fits the ~270 MiB pods; chunk=1024 is
  // blocked by the 315 MiB fp32 enc/ref tensors — verified R15 probe).
  auto bytes_needed = [](size_t chunk) -> size_t {
    auto al = [](size_t n) { return (n + 255) & ~(size_t)255; };
    size_t big = al(chunk * SS * HH * 4);
    return 3 * big + 3 * al(chunk * HH * 8) + al(chunk * 1024 * 8) +
           al(chunk * SS * 4) + 2 * al((size_t)HH * HH * 4) +
           al((size_t)7 * 1024 * 8);
  };
  size_t chunk = 1024;
  if (ws_size < bytes_needed(1024)) chunk = 512;
  if (ws_size < bytes_needed(512)) {
    diag_kernel<<<(2 * BB * SS + 255) / 256, 256, 0, stream>>>(
        out, (float)(ws_size >> 20));
    return;
  }

  char* base_p = (char*)d_ws;
  size_t off = 0;
  auto take = [&](size_t nbytes) {
    void* p = base_p + off;
    off = (off + nbytes + 255) & ~(size_t)255;
    return p;
  };
  const size_t BIGC = chunk * SS * HH;
  float*  enc_c  = (float*)take(BIGC * 4);
  float*  ref_g  = (float*)take(BIGC * 4);
  float*  ref_p  = (float*)take(BIGC * 4);
  double* hA     = (double*)take(chunk * HH * 8);
  double* hB     = (double*)take(chunk * HH * 8);
  double* cbuf   = (double*)take(chunk * HH * 8);
  double* gih    = (double*)take(chunk * 1024 * 8);
  int*    mask   = (int*)take(chunk * SS * 4);
  float*  wqt_g  = (float*)take((size_t)HH * HH * 4);
  float*  wqt_p  = (float*)take((size_t)HH * HH * 4);
  double* P      = (double*)take((size_t)7 * 1024 * 8);

  transpose2<<<HH, HH, 0, stream>>>(glm_wq_w, ptr_wq_w, wqt_g, wqt_p);
  precompute_P<<<28, 256, 0, stream>>>(emb_w, emb_b, start, enc_wih, dec_wih, P);

  const double* Pe   = P;
  const double* Pd   = P + 3 * 1024;
  const double* gih0 = P + 6 * 1024;

  const dim3 lstm_grid((unsigned)chunk / 32, 16);
  for (int cb = 0; cb < BB; cb += (int)chunk) {
    // ---- encoder (h ping-pong) ----
    init_chunk<<<(unsigned)chunk, 256, 0, stream>>>(hA, cbuf);
    double* hin = hA; double* hout = hB;
    for (int t = 0; t < SS; ++t) {
      lstm_gates<true><<<lstm_grid, 256, 0, stream>>>(
          inputs, t, cb, nullptr, Pe,
          enc_whh, enc_bih, enc_bhh, hin, hout, cbuf, enc_c);
      double* tmp = hin; hin = hout; hout = tmp;
    }
    // final h now in hin

    // ---- ref projections (fp32 — HW-verified) ----
    proj_gemm<<<dim3((unsigned)(chunk * SS / 64), 4), 256, 0, stream>>>(
        enc_c, glm_wref_w, glm_wref_b, ref_g);
    proj_gemm<<<dim3((unsigned)(chunk * SS / 64), 4), 256, 0, stream>>>(
        enc_c, ptr_wref_w, ptr_wref_b, ref_p);

    // ---- decoder ----
    init_dec<<<(unsigned)chunk, 256, 0, stream>>>(gih, mask, gih0);
    for (int k = 0; k < SS; ++k) {
      lstm_gates<false><<<lstm_grid, 256, 0, stream>>>(
          inputs, 0, cb, gih, nullptr,
          dec_whh, dec_bih, dec_bhh, hin, hout, cbuf, nullptr);
      dec_attn_sample<<<(unsigned)chunk, 256, 0, stream>>>(
          hout, enc_c, ref_g, ref_p,
          wqt_g, glm_wq_b, glm_v_w, glm_v_b,
          wqt_p, ptr_wq_b, ptr_v_w, ptr_v_b,
          mask, gih, Pd, inputs, out, k, cb);
      double* tmp = hin; hin = hout; hout = tmp;
    }
  }
}